// Round 7
// baseline (614.361 us; speedup 1.0000x reference)
//
#include <hip/hip_runtime.h>
#include <math.h>

// AttenSeq2Seq on a sparse voxel grid. G=32, N=100000, C=96.
// R11 = R10 + latency/MLP fixes on the (now latency-bound) point kernels:
//  - branch-free 8-corner gather (corners are L1/L2-hot after R10's
//    clustering; wgt=0 kills invalid corners; loads go in flight together);
//  - 16B (half8) staging loads in k_point KB=6 (was 8B half4);
//  - 16B (half8) loads in the f16 voxavg kernels (thread = voxel x 12-chunk).
// R10: end-to-end voxel-sorted qv/hv/ebuf/attn (FETCH 62->34MB proven).
// History: R5 mixed-order scatter regression; R6 nt-store regression (nt on
// LOADS only); R7 f16 grids+streams; R8 conv 6-wave M32xN32; R9 v-conv MFMA.
// MFMA layouts (verified): A[m=lane&15][k=(lane>>4)*8+j],
// B[k=(lane>>4)*8+j][n=lane&15], D[row=(lane>>4)*4+reg][col=lane&15].

#define GD 32
#define NV (GD*GD*GD)   // 32768 voxels
#define CH 96

typedef _Float16 half8 __attribute__((ext_vector_type(8)));
typedef _Float16 half4 __attribute__((ext_vector_type(4)));
typedef float f32x4 __attribute__((ext_vector_type(4)));

// ---------------- prep / CSR ----------------

__global__ void k_prep(const float* __restrict__ coords, int* __restrict__ flat,
                       unsigned* __restrict__ cnt, int n) {
  int i = blockIdx.x * 256 + threadIdx.x;
  if (i >= n) return;
  float x = coords[3*i], y = coords[3*i+1], z = coords[3*i+2];
  int ix = (int)floorf(x); ix = ix < 0 ? 0 : (ix > 31 ? 31 : ix);
  int iy = (int)floorf(y); iy = iy < 0 ? 0 : (iy > 31 ? 31 : iy);
  int iz = (int)floorf(z); iz = iz < 0 ? 0 : (iz > 31 ? 31 : iz);
  int f = (ix << 10) + (iy << 5) + iz;
  flat[i] = f;
  atomicAdd(&cnt[f], 1u);
}

// single-block exclusive scan of cnt[NV] -> base, cur; also inv = 1/cnt.
__global__ __launch_bounds__(1024) void k_scan(
    const unsigned* __restrict__ cnt, unsigned* __restrict__ base,
    unsigned* __restrict__ cur, float* __restrict__ inv) {
  __shared__ unsigned part[1024];
  int tid = threadIdx.x;
  int b0 = tid * 32;
  unsigned s = 0;
  for (int i = 0; i < 32; ++i) s += cnt[b0 + i];
  part[tid] = s;
  __syncthreads();
  for (int off = 1; off < 1024; off <<= 1) {
    unsigned t = (tid >= off) ? part[tid - off] : 0u;
    __syncthreads();
    if (tid >= off) part[tid] += t;
    __syncthreads();
  }
  unsigned run = part[tid] - s;   // exclusive base of this chunk
  for (int i = 0; i < 32; ++i) {
    int v = b0 + i;
    unsigned c = cnt[v];
    base[v] = run; cur[v] = run;
    inv[v] = c ? 1.0f / (float)c : 0.0f;
    run += c;
  }
}

__global__ void k_fill(const int* __restrict__ flat, unsigned* __restrict__ cur,
                       int* __restrict__ order, int n) {
  int p = blockIdx.x * 256 + threadIdx.x;
  if (p >= n) return;
  unsigned pos = atomicAdd(&cur[flat[p]], 1u);
  order[pos] = p;
}

// voxel-gather mean -> f16 grid.
// SRCF16: source is f16, thread = (voxel, half8-chunk of 12), 16B loads.
// SRCF16=0: fp32 source, thread = (voxel, float4-chunk of 24).
// SORTED: source stored in CSR order (no order[] indirection).
// PAIR: second half of grid handles (src2 -> dst2).
template<int SCALED, int PAIR, int SRCF16, int SORTED>
__global__ void k_voxavg(const void* __restrict__ src, const float* __restrict__ scale,
                         const unsigned* __restrict__ base, const unsigned* __restrict__ cnt,
                         const float* __restrict__ inv, const int* __restrict__ order,
                         void* __restrict__ dst,
                         const void* __restrict__ src2, void* __restrict__ dst2) {
  constexpr int NC = SRCF16 ? 12 : 24;
  int e = blockIdx.x * 256 + threadIdx.x;   // e < NV*NC (or 2x for PAIR)
  const void* sp = src; void* d = dst;
  if (PAIR && e >= NV * NC) { e -= NV * NC; sp = src2; d = dst2; }
  int v = e / NC, cc = e - v * NC;
  unsigned b = base[v], c = cnt[v];
  if (SRCF16) {
    f32x4 slo = {0.f, 0.f, 0.f, 0.f}, shi = {0.f, 0.f, 0.f, 0.f};
    for (unsigned i = 0; i < c; ++i) {
      int p = SORTED ? (int)(b + i) : order[b + i];
      half8 hx = __builtin_nontemporal_load(reinterpret_cast<const half8*>(sp) + p * 12 + cc);
      f32x4 lo = {(float)hx[0], (float)hx[1], (float)hx[2], (float)hx[3]};
      f32x4 hi = {(float)hx[4], (float)hx[5], (float)hx[6], (float)hx[7]};
      if (SCALED) { float sc = scale[p]; lo *= sc; hi *= sc; }
      slo += lo; shi += hi;
    }
    float iv = inv[v];
    slo *= iv; shi *= iv;
    half8 o = {(_Float16)slo.x, (_Float16)slo.y, (_Float16)slo.z, (_Float16)slo.w,
               (_Float16)shi.x, (_Float16)shi.y, (_Float16)shi.z, (_Float16)shi.w};
    reinterpret_cast<half8*>(d)[e] = o;
  } else {
    f32x4 s = {0.f, 0.f, 0.f, 0.f};
    for (unsigned i = 0; i < c; ++i) {
      int p = SORTED ? (int)(b + i) : order[b + i];
      f32x4 x = __builtin_nontemporal_load(reinterpret_cast<const f32x4*>(sp) + p * 24 + cc);
      if (SCALED) x *= scale[p];
      s += x;
    }
    s *= inv[v];
    union { _Float16 h; unsigned short u; } h0, h1, h2, h3;
    h0.h = (_Float16)s.x; h1.h = (_Float16)s.y; h2.h = (_Float16)s.z; h3.h = (_Float16)s.w;
    ushort4 o; o.x = h0.u; o.y = h1.u; o.z = h2.u; o.w = h3.u;
    reinterpret_cast<ushort4*>(d)[e] = o;
  }
}

// ---------------- merged weight packing ----------------

__device__ __forceinline__ void wpack_one(int e, const float* __restrict__ w,
                                          _Float16* __restrict__ wp, int nch) {
  int j = e & 7; int l = (e >> 3) & 63; int r = e >> 9;
  int cot = r % 6; r /= 6; int chk = r % nch; int tap = r / nch;
  int Ci = nch * 32;
  int ci = chk * 32 + (l >> 4) * 8 + j;
  int co = cot * 16 + (l & 15);
  wp[e] = (_Float16)w[(co * Ci + ci) * 27 + tap];
}

__device__ __forceinline__ void linpack_one(int e, const float* __restrict__ w,
                                            _Float16* __restrict__ wl, int kb) {
  int j = e & 7; int l = (e >> 3) & 63; int r = e >> 9;
  int nt = r % 6; int kt = r / 6;
  int Ci = kb * 32;
  int ci = kt * 32 + (l >> 4) * 8 + j;
  int co = nt * 16 + (l & 15);
  wl[e] = (_Float16)w[co * Ci + ci];
}

#define WP3 (27*3*6*512)
#define WP6 (27*6*6*512)
#define WL3 (3*6*512)
#define WL6 (6*6*512)
#define WV2 (27*512)    // v-conv B-fragments: [chunk3][col9][lane64][j8]
#define PACK_TOTAL (2*WP3 + 2*WP6 + 2*WL3 + 2*WL6 + WV2)

__global__ void k_packall(
    const float* __restrict__ wq, const float* __restrict__ wh,
    const float* __restrict__ wa, const float* __restrict__ wu,
    const float* __restrict__ lq, const float* __restrict__ lh,
    const float* __restrict__ la, const float* __restrict__ lu,
    const float* __restrict__ wvc,
    _Float16* __restrict__ wpq, _Float16* __restrict__ wph,
    _Float16* __restrict__ wpa, _Float16* __restrict__ wpu,
    _Float16* __restrict__ wlq, _Float16* __restrict__ wlh,
    _Float16* __restrict__ wla, _Float16* __restrict__ wlu,
    _Float16* __restrict__ wt2) {
  int e = blockIdx.x * 256 + threadIdx.x;
  if (e < WP3) { wpack_one(e, wq, wpq, 3); return; } e -= WP3;
  if (e < WP3) { wpack_one(e, wh, wph, 3); return; } e -= WP3;
  if (e < WP6) { wpack_one(e, wa, wpa, 6); return; } e -= WP6;
  if (e < WP6) { wpack_one(e, wu, wpu, 6); return; } e -= WP6;
  if (e < WL3) { linpack_one(e, lq, wlq, 3); return; } e -= WL3;
  if (e < WL3) { linpack_one(e, lh, wlh, 3); return; } e -= WL3;
  if (e < WL6) { linpack_one(e, la, wla, 6); return; } e -= WL6;
  if (e < WL6) { linpack_one(e, lu, wlu, 6); return; } e -= WL6;
  if (e < WV2) {
    // B[k=(l>>4)*8+j][n=l&15] = (n<3) ? wvc[ci*27 + col9*3 + n] : 0
    int j = e & 7; int l = (e >> 3) & 63; int r = e >> 9;   // r in 0..26
    int col9 = r % 9, chunk = r / 9;
    int n = l & 15, kq = l >> 4;
    int ci = chunk * 32 + kq * 8 + j;
    wt2[e] = (n < 3) ? (_Float16)wvc[ci * 27 + col9 * 3 + n] : (_Float16)0.f;
  }
}

// ---------------- MFMA 3x3x3 conv ----------------
// R8: 384 threads, 6 waves = (column msel) x (cout-pair npair).
// Each wave: M=32 (column msel, both z-halves) x N=32 (couts npair*32..+32).
// Per tap: 2 A ds_reads + 2 B loads -> 4 MFMAs (2x B-reuse, 2x A-reuse).
// Block = 2 z-columns (x, y0), (x, y0+1). LDS halo 12 cols x 34 z x 32 ci f16
// (rows padded to 40) = 32640 B. Output grid f16.
// PAIR: blocks [512, 1024) run the second (gA2, wp2, out2) problem.
template<int NCH, int PAIR>   // NCH: 3 (Cin=96) or 6 (Cin=192, 2nd 96 from gB)
__global__ __launch_bounds__(384, 4) void k_conv_mfma(
    const _Float16* __restrict__ gA, const _Float16* __restrict__ gB,
    const half8* __restrict__ wp, _Float16* __restrict__ out,
    const _Float16* __restrict__ gA2, const half8* __restrict__ wp2,
    _Float16* __restrict__ out2) {
  __shared__ unsigned short ls[12 * 34 * 40];
  int bid = blockIdx.x;
  const _Float16* ga = gA; const _Float16* gb = gB;
  const half8* w = wp; _Float16* o = out;
  if (PAIR && bid >= 512) { bid -= 512; ga = gA2; gb = gA2; w = wp2; o = out2; }
  int bx = bid >> 4, y0 = (bid & 15) * 2;
  int tid = threadIdx.x;
  int lane = tid & 63, wv = tid >> 6;    // 6 waves
  int msel = wv & 1, npair = wv >> 1;    // column sel (M=32), cout pair (N=32)
  int lrow = lane & 15, quad = lane >> 4;

  f32x4 acc[2][2];   // [mt][nb]
#pragma unroll
  for (int i = 0; i < 2; ++i)
#pragma unroll
    for (int j = 0; j < 2; ++j) acc[i][j] = (f32x4){0.f, 0.f, 0.f, 0.f};

  for (int chunk = 0; chunk < NCH; ++chunk) {
    const _Float16* g = (NCH == 6 && chunk >= 3) ? gb : ga;
    int cbase = ((NCH == 6 && chunk >= 3) ? chunk - 3 : chunk) * 32;
    __syncthreads();
    for (int e = tid; e < 12 * 34 * 4; e += 384) {
      int ciu = e & 3; int zc = e >> 2;
      int zz = zc % 34; int sc = zc / 34;
      int dx = sc >> 2, dyy = sc & 3;
      int x = bx + dx - 1, y = y0 + dyy - 1, zv = zz - 1;
      uint4 val = {0u, 0u, 0u, 0u};
      if ((unsigned)x < 32u && (unsigned)y < 32u && (unsigned)zv < 32u)
        val = *reinterpret_cast<const uint4*>(
            g + (size_t)((x << 10) + (y << 5) + zv) * CH + cbase + ciu * 8);
      *reinterpret_cast<uint4*>(&ls[(sc * 34 + zz) * 40 + ciu * 8]) = val;
    }
    __syncthreads();
#pragma unroll
    for (int dx9 = 0; dx9 < 3; ++dx9)
#pragma unroll
      for (int dy9 = 0; dy9 < 3; ++dy9) {
        int sc = dx9 * 4 + msel + dy9;
        const unsigned short* lbase = &ls[(sc * 34) * 40 + quad * 8];
        int tap0 = (dx9 * 3 + dy9) * 3;
#pragma unroll
        for (int dz = 0; dz < 3; ++dz) {
          half8 a0 = *reinterpret_cast<const half8*>(&lbase[(lrow + dz) * 40]);
          half8 a1 = *reinterpret_cast<const half8*>(&lbase[(16 + lrow + dz) * 40]);
          const half8* wb = w + ((size_t)((tap0 + dz) * NCH + chunk) * 6 + npair * 2) * 64 + lane;
          half8 b0 = wb[0];
          half8 b1 = wb[64];
          acc[0][0] = __builtin_amdgcn_mfma_f32_16x16x32_f16(a0, b0, acc[0][0], 0, 0, 0);
          acc[1][0] = __builtin_amdgcn_mfma_f32_16x16x32_f16(a1, b0, acc[1][0], 0, 0, 0);
          acc[0][1] = __builtin_amdgcn_mfma_f32_16x16x32_f16(a0, b1, acc[0][1], 0, 0, 0);
          acc[1][1] = __builtin_amdgcn_mfma_f32_16x16x32_f16(a1, b1, acc[1][1], 0, 0, 0);
        }
      }
  }
  int y = y0 + msel;
  int vb = (bx << 10) + (y << 5);
#pragma unroll
  for (int mt = 0; mt < 2; ++mt)
#pragma unroll
    for (int nb = 0; nb < 2; ++nb)
#pragma unroll
      for (int r = 0; r < 4; ++r) {
        int z = mt * 16 + quad * 4 + r;
        o[(size_t)(vb + z) * CH + (npair * 2 + nb) * 16 + lrow] = (_Float16)acc[mt][nb][r];
      }
}

// Cout=1 conv (the 'v' attention head) via MFMA taps-in-N (R9).
__global__ __launch_bounds__(128) void k_conv3d_v2(
    const _Float16* __restrict__ g, const _Float16* __restrict__ wt2,
    float* __restrict__ out) {
  __shared__ unsigned short ls[12 * 48 * 32];
  __shared__ float dl[2][48][4];
  int bid = blockIdx.x;            // 512 blocks: bx = bid>>4, y0 = (bid&15)*2
  int bx = bid >> 4, y0 = (bid & 15) * 2;
  int tid = threadIdx.x;
  int lane = tid & 63, wv = tid >> 6;
  int lrow = lane & 15, quad = lane >> 4;

  f32x4 acc[3];
#pragma unroll
  for (int i = 0; i < 3; ++i) acc[i] = (f32x4){0.f, 0.f, 0.f, 0.f};

  for (int chunk = 0; chunk < 3; ++chunk) {
    __syncthreads();
#pragma unroll 3
    for (int it = 0; it < 18; ++it) {
      int e = it * 128 + tid;
      int c8 = e & 3;
      int t = e >> 2;              // col*48 + zz
      int col = t / 48;
      int zz = t - col * 48;
      int dx = col >> 2, dyy = col & 3;
      int x = bx + dx - 1, y = y0 + dyy - 1, zv = zz - 1;
      uint4 val = {0u, 0u, 0u, 0u};
      if ((unsigned)x < 32u && (unsigned)y < 32u && (unsigned)zv < 32u)
        val = *reinterpret_cast<const uint4*>(
            g + (size_t)((x << 10) + (y << 5) + zv) * CH + chunk * 32 + c8 * 8);
      *reinterpret_cast<uint4*>(&ls[(t << 5) + ((c8 ^ (zz & 3)) << 3)]) = val;
    }
    __syncthreads();
#pragma unroll
    for (int dx9 = 0; dx9 < 3; ++dx9)
#pragma unroll
      for (int dy9 = 0; dy9 < 3; ++dy9) {
        int col9 = dx9 * 3 + dy9;
        int sc = dx9 * 4 + wv + dy9;
        half8 b = *reinterpret_cast<const half8*>(
            wt2 + (size_t)((chunk * 9 + col9) << 9) + (lane << 3));
#pragma unroll
        for (int mt = 0; mt < 3; ++mt) {
          int zz = mt * 16 + lrow;
          half8 a = *reinterpret_cast<const half8*>(
              &ls[((sc * 48 + zz) << 5) + ((quad ^ (zz & 3)) << 3)]);
          acc[mt] = __builtin_amdgcn_mfma_f32_16x16x32_f16(a, b, acc[mt], 0, 0, 0);
        }
      }
  }
  if (lrow < 3) {
#pragma unroll
    for (int mt = 0; mt < 3; ++mt)
#pragma unroll
      for (int r = 0; r < 4; ++r)
        dl[wv][mt * 16 + quad * 4 + r][lrow] = acc[mt][r];
  }
  __syncthreads();
  if (tid < 64) {
    int z = tid & 31, yb = tid >> 5;
    float v = dl[yb][z][0] + dl[yb][z + 1][1] + dl[yb][z + 2][2];
    out[(bx << 10) + ((y0 + yb) << 5) + z] = v;
  }
}

// ---------------- fused point kernel: MFMA linear + trilinear devox ----------------

__device__ __forceinline__ void corner_one(
    const float* __restrict__ coords, const unsigned* __restrict__ cnt,
    int p, int k, int& flc, float& w) {
  float cx = coords[3*p], cy = coords[3*p+1], cz = coords[3*p+2];
  float bx = floorf(cx), by = floorf(cy), bz = floorf(cz);
  float fx = cx - bx, fy = cy - by, fz = cz - bz;
  int dx = (k >> 2) & 1, dy = (k >> 1) & 1, dzz = k & 1;
  int ix = (int)bx + dx, iy = (int)by + dy, iz = (int)bz + dzz;
  bool valid = ((unsigned)ix < 32u) && ((unsigned)iy < 32u) && ((unsigned)iz < 32u);
  int xc = min(max(ix, 0), 31), yc = min(max(iy, 0), 31), zc = min(max(iz, 0), 31);
  flc = (xc << 10) + (yc << 5) + zc;
  float wx = dx ? fx : 1.f - fx;
  float wy = dy ? fy : 1.f - fy;
  float wz = dzz ? fz : 1.f - fz;
  w = (valid && cnt[flc] > 0u) ? wx * wy * wz : 0.f;
}

// R10: block handles sorted slots [p0, p0+64); physical point p = order[idx].
// KB: 3 (K=96, X fp32 ORIGINAL-order inputs query/hidden, gathered via lord)
//     or 6 (K=192, X = [X1, X2] f16 SORTED streams, read sequentially).
// MODE: 0 = plain (dst = devox+lin+b, f16 SORTED out), 1 = energy (tanh, f16
//       SORTED out + attn partial -> attn_out[idx] SORTED), 2 = final (tanh;
//       X2 scaled by SORTED scale; fp32 out scattered to out[p]).
// PAIR (MODE 0 only): blocks [npt, 2npt) run (outv2, X1b, wl2, lb2 -> dst2).
template<int KB, int MODE, int PAIR>
__global__ __launch_bounds__(256) void k_point(
    const _Float16* __restrict__ outv, const void* __restrict__ X1, const void* __restrict__ X2,
    const float* __restrict__ scale, const half8* __restrict__ wl,
    const float* __restrict__ lb, const float* __restrict__ vlw,
    const float* __restrict__ coords, const unsigned* __restrict__ cnt,
    const int* __restrict__ order,
    void* __restrict__ dst, float* __restrict__ attn_out, int n,
    const _Float16* __restrict__ outv2, const void* __restrict__ X1b,
    const half8* __restrict__ wl2, const float* __restrict__ lb2,
    void* __restrict__ dst2) {
  __shared__ char us[64 * 100 * 4];   // union: f16 A-stage [64][KB*32+8] / fp32 acc [64][100]
  __shared__ int lflc[512];
  __shared__ float lcw[512];
  __shared__ int lord[64];
  constexpr int APITCH = KB * 32 + 8;
  constexpr int XF16 = (KB == 6);      // sorted f16 inter-stage streams
  constexpr int OUTF16 = (MODE != 2);  // final output stays fp32
  int tid = threadIdx.x;
  int bid = blockIdx.x;
  const _Float16* ov = outv; const void* x1 = X1;
  const half8* w = wl; const float* b = lb; void* d = dst;
  if (PAIR) {
    int npt = (n + 63) >> 6;
    if (bid >= npt) { bid -= npt; ov = outv2; x1 = X1b; w = wl2; b = lb2; d = dst2; }
  }
  int p0 = bid * 64;

  if (tid < 64) lord[tid] = (p0 + tid < n) ? order[p0 + tid] : 0;
  __syncthreads();

  // corner table (physical point p -> clustered voxels, L2-local)
  for (int e = tid; e < 512; e += 256) {
    int j = e >> 3, k = e & 7;
    int f = 0; float wgt = 0.f;
    if (p0 + j < n) corner_one(coords, cnt, lord[j], k, f, wgt);
    lflc[e] = f; lcw[e] = wgt;
  }

  // stage A (f16) into LDS
  unsigned short* lsa = reinterpret_cast<unsigned short*>(us);
  if (XF16) {
    // 16B half8 loads: KB*4 chunks per point (=24 for KB=6)
    for (int e = tid; e < 64 * KB * 4; e += 256) {
      int j = e / (KB * 4);
      int q8 = e - j * (KB * 4);
      int idx = p0 + j;
      half8 hx = {(_Float16)0.f, (_Float16)0.f, (_Float16)0.f, (_Float16)0.f,
                  (_Float16)0.f, (_Float16)0.f, (_Float16)0.f, (_Float16)0.f};
      if (idx < n) {
        if (q8 < 12) {
          hx = __builtin_nontemporal_load(reinterpret_cast<const half8*>(x1) + idx * 12 + q8);
        } else {
          hx = __builtin_nontemporal_load(reinterpret_cast<const half8*>(X2) + idx * 12 + (q8 - 12));
          if (MODE == 2) {
            float sc = scale[idx];
#pragma unroll
            for (int u = 0; u < 8; ++u) hx[u] = (_Float16)((float)hx[u] * sc);
          }
        }
      }
      *reinterpret_cast<half8*>(&lsa[j * APITCH + q8 * 8]) = hx;
    }
  } else {
    for (int e = tid; e < 64 * KB * 8; e += 256) {
      int j = e / (KB * 8);
      int q4 = e - j * (KB * 8);
      int idx = p0 + j;
      // original-order fp32 inputs: 24 consecutive threads fetch one 384B row
      f32x4 v = {0.f, 0.f, 0.f, 0.f};
      if (idx < n)
        v = __builtin_nontemporal_load(
            reinterpret_cast<const f32x4*>(x1) + (size_t)lord[j] * 24 + q4);
      union { _Float16 h; unsigned short u; } h0, h1, h2, h3;
      h0.h = (_Float16)v.x; h1.h = (_Float16)v.y; h2.h = (_Float16)v.z; h3.h = (_Float16)v.w;
      ushort4 o; o.x = h0.u; o.y = h1.u; o.z = h2.u; o.w = h3.u;
      *reinterpret_cast<ushort4*>(&lsa[j * APITCH + q4 * 4]) = o;
    }
  }
  __syncthreads();

  // MFMA: wave wv handles rows [wv*16, wv*16+16), full N=96.
  int lane = tid & 63, wv = tid >> 6;
  int lrow = lane & 15, quad = lane >> 4;
  f32x4 acc[6];
#pragma unroll
  for (int i = 0; i < 6; ++i) acc[i] = (f32x4){0.f, 0.f, 0.f, 0.f};
#pragma unroll
  for (int kt = 0; kt < KB; ++kt) {
    half8 a = *reinterpret_cast<const half8*>(&lsa[(wv * 16 + lrow) * APITCH + kt * 32 + quad * 8]);
    const half8* wb = w + (size_t)(kt * 6) * 64 + lane;
#pragma unroll
    for (int nt = 0; nt < 6; ++nt)
      acc[nt] = __builtin_amdgcn_mfma_f32_16x16x32_f16(a, wb[(size_t)nt * 64], acc[nt], 0, 0, 0);
  }
  __syncthreads();   // done reading lsa; reuse as fp32 acc
  float* lacc = reinterpret_cast<float*>(us);
#pragma unroll
  for (int nt = 0; nt < 6; ++nt)
#pragma unroll
    for (int r = 0; r < 4; ++r)
      lacc[(wv * 16 + quad * 4 + r) * 100 + nt * 16 + lrow] = acc[nt][r];
  __syncthreads();

  // point-major epilogue: 4 threads/point x 24 channels.
  int pt = tid >> 2, sub = tid & 3;
  int idx = p0 + pt;
  bool valid = idx < n;
  f32x4 a[6];
  const float* lrow_p = &lacc[pt * 100 + sub * 24];
#pragma unroll
  for (int i = 0; i < 6; ++i) a[i] = *reinterpret_cast<const f32x4*>(lrow_p + i * 4);
  const f32x4* lb4 = reinterpret_cast<const f32x4*>(b + sub * 24);
#pragma unroll
  for (int i = 0; i < 6; ++i) a[i] += lb4[i];
  // branch-free 8-corner gather from the f16 grid (48B/thread/corner).
  // Corners are clustered (sorted blocks) -> L1/L2-hot; wgt=0 kills invalid
  // corners; unconditional loads give the scheduler full MLP.
#pragma unroll
  for (int k = 0; k < 8; ++k) {
    float wgt = lcw[pt * 8 + k];
    const half8* op = reinterpret_cast<const half8*>(ov + (size_t)lflc[pt * 8 + k] * CH + sub * 24);
    half8 o0 = op[0], o1 = op[1], o2 = op[2];
    f32x4 t;
    t = (f32x4){(float)o0[0], (float)o0[1], (float)o0[2], (float)o0[3]}; a[0] += wgt * t;
    t = (f32x4){(float)o0[4], (float)o0[5], (float)o0[6], (float)o0[7]}; a[1] += wgt * t;
    t = (f32x4){(float)o1[0], (float)o1[1], (float)o1[2], (float)o1[3]}; a[2] += wgt * t;
    t = (f32x4){(float)o1[4], (float)o1[5], (float)o1[6], (float)o1[7]}; a[3] += wgt * t;
    t = (f32x4){(float)o2[0], (float)o2[1], (float)o2[2], (float)o2[3]}; a[4] += wgt * t;
    t = (f32x4){(float)o2[4], (float)o2[5], (float)o2[6], (float)o2[7]}; a[5] += wgt * t;
  }
  if (MODE >= 1) {
#pragma unroll
    for (int i = 0; i < 6; ++i) {
      a[i].x = tanhf(a[i].x); a[i].y = tanhf(a[i].y);
      a[i].z = tanhf(a[i].z); a[i].w = tanhf(a[i].w);
    }
  }
  if (valid) {
    if (OUTF16) {
      // sorted f16 stream out
      _Float16* dh = reinterpret_cast<_Float16*>(d) + (size_t)idx * CH + sub * 24;
      uint4* du = reinterpret_cast<uint4*>(dh);
#pragma unroll
      for (int i = 0; i < 3; ++i) {
        union { _Float16 h[8]; uint4 q; } t;
        t.h[0] = (_Float16)a[2*i].x;   t.h[1] = (_Float16)a[2*i].y;
        t.h[2] = (_Float16)a[2*i].z;   t.h[3] = (_Float16)a[2*i].w;
        t.h[4] = (_Float16)a[2*i+1].x; t.h[5] = (_Float16)a[2*i+1].y;
        t.h[6] = (_Float16)a[2*i+1].z; t.h[7] = (_Float16)a[2*i+1].w;
        du[i] = t.q;
      }
    } else {
      // final output: scatter full 384B fp32 row to original position
      f32x4* d4 = reinterpret_cast<f32x4*>(d) + (size_t)lord[pt] * 24 + sub * 6;
#pragma unroll
      for (int i = 0; i < 6; ++i) d4[i] = a[i];
    }
  }
  if (MODE == 1) {
    const f32x4* vw4 = reinterpret_cast<const f32x4*>(vlw + sub * 24);
    float partial = 0.f;
#pragma unroll
    for (int i = 0; i < 6; ++i) {
      f32x4 vw = vw4[i];
      partial += a[i].x * vw.x + a[i].y * vw.y + a[i].z * vw.z + a[i].w * vw.w;
    }
    partial += __shfl_xor(partial, 1);
    partial += __shfl_xor(partial, 2);
    if (sub == 0 && valid) attn_out[idx] = partial;   // sorted
  }
}

// attn (sorted) += v_lb + trilinear(Ov); physical point via order[].
__global__ void k_attn_final(const float* __restrict__ outvV, const float* __restrict__ vlb,
                             const float* __restrict__ coords, const unsigned* __restrict__ cnt,
                             const int* __restrict__ order,
                             float* __restrict__ attn, int n) {
  int idx = blockIdx.x * 256 + threadIdx.x;
  if (idx >= n) return;
  int p = order[idx];
  float a = attn[idx] + vlb[0];
#pragma unroll
  for (int k = 0; k < 8; ++k) {
    int f; float w;
    corner_one(coords, cnt, p, k, f, w);
    a += w * outvV[f];
  }
  attn[idx] = a;
}

// ---------------- launch ----------------

extern "C" void kernel_launch(void* const* d_in, const int* in_sizes, int n_in,
                              void* d_out, int out_size, void* d_ws, size_t ws_size,
                              hipStream_t stream) {
  const float* hidden   = (const float*)d_in[0];
  const float* query    = (const float*)d_in[1];
  const float* coords   = (const float*)d_in[2];
  const float* wq_conv  = (const float*)d_in[3];
  const float* wq_lw    = (const float*)d_in[4];
  const float* wq_lb    = (const float*)d_in[5];
  const float* wh_conv  = (const float*)d_in[6];
  const float* wh_lw    = (const float*)d_in[7];
  const float* wh_lb    = (const float*)d_in[8];
  const float* att_conv = (const float*)d_in[9];
  const float* att_lw   = (const float*)d_in[10];
  const float* att_lb   = (const float*)d_in[11];
  const float* v_conv   = (const float*)d_in[12];
  const float* v_lw     = (const float*)d_in[13];
  const float* v_lb     = (const float*)d_in[14];
  const float* upd_conv = (const float*)d_in[15];
  const float* upd_lw   = (const float*)d_in[16];
  const float* upd_lb   = (const float*)d_in[17];
  float* out = (float*)d_out;
  const int n = in_sizes[0] / CH;

  char* wsp = (char*)d_ws;
  auto alloc = [&](size_t bytes) {
    char* r = wsp;
    wsp += (bytes + 255) & ~(size_t)255;
    return r;
  };
  int*      flat  = (int*)     alloc((size_t)n * 4);
  int*      order = (int*)     alloc((size_t)n * 4);
  unsigned* cnt   = (unsigned*)alloc((size_t)NV * 4);
  unsigned* base  = (unsigned*)alloc((size_t)NV * 4);
  unsigned* cur   = (unsigned*)alloc((size_t)NV * 4);
  float*    inv   = (float*)   alloc((size_t)NV * 4);
  float*    attn  = (float*)   alloc((size_t)n * 4);   // SORTED order
  _Float16* wt2   = (_Float16*)alloc((size_t)WV2 * 2);
  _Float16* wpq = (_Float16*)alloc((size_t)WP3 * 2);
  _Float16* wph = (_Float16*)alloc((size_t)WP3 * 2);
  _Float16* wpa = (_Float16*)alloc((size_t)WP6 * 2);
  _Float16* wpu = (_Float16*)alloc((size_t)WP6 * 2);
  _Float16* wlq = (_Float16*)alloc((size_t)WL3 * 2);
  _Float16* wlh = (_Float16*)alloc((size_t)WL3 * 2);
  _Float16* wla = (_Float16*)alloc((size_t)WL6 * 2);
  _Float16* wlu = (_Float16*)alloc((size_t)WL6 * 2);
  _Float16* Hq  = (_Float16*)alloc((size_t)NV * CH * 2);
  _Float16* Hh  = (_Float16*)alloc((size_t)NV * CH * 2);
  _Float16* H1  = (_Float16*)alloc((size_t)NV * CH * 2);
  _Float16* H2  = (_Float16*)alloc((size_t)NV * CH * 2);
  _Float16* O1  = (_Float16*)alloc((size_t)NV * CH * 2);
  _Float16* O2  = (_Float16*)alloc((size_t)NV * CH * 2);
  float* Ov   = (float*)alloc((size_t)NV * 4);
  _Float16* qv   = (_Float16*)alloc((size_t)n * CH * 2);   // SORTED order
  _Float16* hv   = (_Float16*)alloc((size_t)n * CH * 2);   // SORTED order
  _Float16* ebuf = (_Float16*)alloc((size_t)n * CH * 2);   // SORTED order

  const int nb  = (n + 255) / 256;
  const int npt = (n + 63) / 64;
  const int nva   = NV * 24 / 256;   // 3072 (fp32 source: 24 chunks)
  const int nva16 = NV * 12 / 256;   // 1536 (f16 source: 12 half8 chunks)

  // prep: CSR + merged weight packing
  hipMemsetAsync(cnt, 0, (size_t)NV * 4, stream);
  k_prep<<<nb, 256, 0, stream>>>(coords, flat, cnt, n);
  k_scan<<<1, 1024, 0, stream>>>(cnt, base, cur, inv);
  k_fill<<<nb, 256, 0, stream>>>(flat, cur, order, n);
  k_packall<<<(PACK_TOTAL + 255) / 256, 256, 0, stream>>>(
      wq_conv, wh_conv, att_conv, upd_conv, wq_lw, wh_lw, att_lw, upd_lw, v_conv,
      wpq, wph, wpa, wpu, wlq, wlh, wla, wlu, wt2);

  // stages 1+2 (merged): q = sconv(query), h = sconv(hidden)
  k_voxavg<0,1,0,0><<<2*nva, 256, 0, stream>>>(query, nullptr, base, cnt, inv, order,
                                               Hq, hidden, Hh);
  k_conv_mfma<3,1><<<1024, 384, 0, stream>>>(Hq, Hq, (const half8*)wpq, O1,
                                             Hh, (const half8*)wph, O2);
  k_point<3,0,1><<<2*npt, 256, 0, stream>>>(O1, query, nullptr, nullptr, (const half8*)wlq,
                                            wq_lb, nullptr, coords, cnt, order, qv, nullptr, n,
                                            O2, hidden, (const half8*)wlh, wh_lb, hv);

  // stage 3: energy = tanh(sconv([h,q])) -> ebuf (f16 sorted) + v partial (attn sorted)
  k_voxavg<0,1,1,1><<<2*nva16, 256, 0, stream>>>(hv, nullptr, base, cnt, inv, order,
                                                 H1, qv, H2);
  k_conv_mfma<6,0><<<512, 384, 0, stream>>>(H1, H2, (const half8*)wpa, O1,
                                            nullptr, nullptr, nullptr);
  k_point<6,1,0><<<npt, 256, 0, stream>>>(O1, hv, qv, nullptr, (const half8*)wla,
                                          att_lb, v_lw, coords, cnt, order, ebuf, attn, n,
                                          nullptr, nullptr, nullptr, nullptr, nullptr);

  // stage 4: attn = sconv(energy) with Cout=1 (f16 grid, MFMA taps-in-N)
  k_voxavg<0,0,1,1><<<nva16, 256, 0, stream>>>(ebuf, nullptr, base, cnt, inv, order,
                                               Hq, nullptr, nullptr);
  k_conv3d_v2<<<512, 128, 0, stream>>>(Hq, wt2, Ov);
  k_attn_final<<<nb, 256, 0, stream>>>(Ov, v_lb, coords, cnt, order, attn, n);

  // stage 5: out = tanh(sconv([q, attn*h]))
  k_voxavg<1,0,1,1><<<nva16, 256, 0, stream>>>(hv, attn, base, cnt, inv, order,
                                               H1, nullptr, nullptr);
  k_conv_mfma<6,0><<<512, 384, 0, stream>>>(H2, H1, (const half8*)wpu, O1,
                                            nullptr, nullptr, nullptr);
  k_point<6,2,0><<<npt, 256, 0, stream>>>(O1, qv, hv, attn, (const half8*)wlu,
                                          upd_lb, nullptr, coords, cnt, order, out, nullptr, n,
                                          nullptr, nullptr, nullptr, nullptr, nullptr);
}

// Round 8
// 580.574 us; speedup vs baseline: 1.0582x; 1.0582x over previous
//
#include <hip/hip_runtime.h>
#include <math.h>

// AttenSeq2Seq on a sparse voxel grid. G=32, N=100000, C=96.
// R12 = R11 with the corner-gather GUARD restored. R11's branch-free gather
// let the compiler hoist 8x3 half8 loads -> VGPR 44->92, occupancy 37->16%
// (latency-bound kernel lost its TLP). The guard throttles hoisting.
// Kept from R11: half8 (16B) staging loads in k_point KB=6, half8 voxavg.
// Kept from R10: end-to-end voxel-sorted qv/hv/ebuf/attn storage.
// History: R5 mixed-order scatter regression; R6 nt-store regression (nt on
// LOADS only); R7 f16 grids+streams; R8 conv 6-wave M32xN32; R9 v-conv MFMA;
// R11 branch-free-gather VGPR regression (guard = occupancy throttle).
// MFMA layouts (verified): A[m=lane&15][k=(lane>>4)*8+j],
// B[k=(lane>>4)*8+j][n=lane&15], D[row=(lane>>4)*4+reg][col=lane&15].

#define GD 32
#define NV (GD*GD*GD)   // 32768 voxels
#define CH 96

typedef _Float16 half8 __attribute__((ext_vector_type(8)));
typedef _Float16 half4 __attribute__((ext_vector_type(4)));
typedef float f32x4 __attribute__((ext_vector_type(4)));

// ---------------- prep / CSR ----------------

__global__ void k_prep(const float* __restrict__ coords, int* __restrict__ flat,
                       unsigned* __restrict__ cnt, int n) {
  int i = blockIdx.x * 256 + threadIdx.x;
  if (i >= n) return;
  float x = coords[3*i], y = coords[3*i+1], z = coords[3*i+2];
  int ix = (int)floorf(x); ix = ix < 0 ? 0 : (ix > 31 ? 31 : ix);
  int iy = (int)floorf(y); iy = iy < 0 ? 0 : (iy > 31 ? 31 : iy);
  int iz = (int)floorf(z); iz = iz < 0 ? 0 : (iz > 31 ? 31 : iz);
  int f = (ix << 10) + (iy << 5) + iz;
  flat[i] = f;
  atomicAdd(&cnt[f], 1u);
}

// single-block exclusive scan of cnt[NV] -> base, cur; also inv = 1/cnt.
__global__ __launch_bounds__(1024) void k_scan(
    const unsigned* __restrict__ cnt, unsigned* __restrict__ base,
    unsigned* __restrict__ cur, float* __restrict__ inv) {
  __shared__ unsigned part[1024];
  int tid = threadIdx.x;
  int b0 = tid * 32;
  unsigned s = 0;
  for (int i = 0; i < 32; ++i) s += cnt[b0 + i];
  part[tid] = s;
  __syncthreads();
  for (int off = 1; off < 1024; off <<= 1) {
    unsigned t = (tid >= off) ? part[tid - off] : 0u;
    __syncthreads();
    if (tid >= off) part[tid] += t;
    __syncthreads();
  }
  unsigned run = part[tid] - s;   // exclusive base of this chunk
  for (int i = 0; i < 32; ++i) {
    int v = b0 + i;
    unsigned c = cnt[v];
    base[v] = run; cur[v] = run;
    inv[v] = c ? 1.0f / (float)c : 0.0f;
    run += c;
  }
}

__global__ void k_fill(const int* __restrict__ flat, unsigned* __restrict__ cur,
                       int* __restrict__ order, int n) {
  int p = blockIdx.x * 256 + threadIdx.x;
  if (p >= n) return;
  unsigned pos = atomicAdd(&cur[flat[p]], 1u);
  order[pos] = p;
}

// voxel-gather mean -> f16 grid.
// SRCF16: source is f16, thread = (voxel, half8-chunk of 12), 16B loads.
// SRCF16=0: fp32 source, thread = (voxel, float4-chunk of 24).
// SORTED: source stored in CSR order (no order[] indirection).
// PAIR: second half of grid handles (src2 -> dst2).
template<int SCALED, int PAIR, int SRCF16, int SORTED>
__global__ void k_voxavg(const void* __restrict__ src, const float* __restrict__ scale,
                         const unsigned* __restrict__ base, const unsigned* __restrict__ cnt,
                         const float* __restrict__ inv, const int* __restrict__ order,
                         void* __restrict__ dst,
                         const void* __restrict__ src2, void* __restrict__ dst2) {
  constexpr int NC = SRCF16 ? 12 : 24;
  int e = blockIdx.x * 256 + threadIdx.x;   // e < NV*NC (or 2x for PAIR)
  const void* sp = src; void* d = dst;
  if (PAIR && e >= NV * NC) { e -= NV * NC; sp = src2; d = dst2; }
  int v = e / NC, cc = e - v * NC;
  unsigned b = base[v], c = cnt[v];
  if (SRCF16) {
    f32x4 slo = {0.f, 0.f, 0.f, 0.f}, shi = {0.f, 0.f, 0.f, 0.f};
    for (unsigned i = 0; i < c; ++i) {
      int p = SORTED ? (int)(b + i) : order[b + i];
      half8 hx = __builtin_nontemporal_load(reinterpret_cast<const half8*>(sp) + p * 12 + cc);
      f32x4 lo = {(float)hx[0], (float)hx[1], (float)hx[2], (float)hx[3]};
      f32x4 hi = {(float)hx[4], (float)hx[5], (float)hx[6], (float)hx[7]};
      if (SCALED) { float sc = scale[p]; lo *= sc; hi *= sc; }
      slo += lo; shi += hi;
    }
    float iv = inv[v];
    slo *= iv; shi *= iv;
    half8 o = {(_Float16)slo.x, (_Float16)slo.y, (_Float16)slo.z, (_Float16)slo.w,
               (_Float16)shi.x, (_Float16)shi.y, (_Float16)shi.z, (_Float16)shi.w};
    reinterpret_cast<half8*>(d)[e] = o;
  } else {
    f32x4 s = {0.f, 0.f, 0.f, 0.f};
    for (unsigned i = 0; i < c; ++i) {
      int p = SORTED ? (int)(b + i) : order[b + i];
      f32x4 x = __builtin_nontemporal_load(reinterpret_cast<const f32x4*>(sp) + p * 24 + cc);
      if (SCALED) x *= scale[p];
      s += x;
    }
    s *= inv[v];
    union { _Float16 h; unsigned short u; } h0, h1, h2, h3;
    h0.h = (_Float16)s.x; h1.h = (_Float16)s.y; h2.h = (_Float16)s.z; h3.h = (_Float16)s.w;
    ushort4 o; o.x = h0.u; o.y = h1.u; o.z = h2.u; o.w = h3.u;
    reinterpret_cast<ushort4*>(d)[e] = o;
  }
}

// ---------------- merged weight packing ----------------

__device__ __forceinline__ void wpack_one(int e, const float* __restrict__ w,
                                          _Float16* __restrict__ wp, int nch) {
  int j = e & 7; int l = (e >> 3) & 63; int r = e >> 9;
  int cot = r % 6; r /= 6; int chk = r % nch; int tap = r / nch;
  int Ci = nch * 32;
  int ci = chk * 32 + (l >> 4) * 8 + j;
  int co = cot * 16 + (l & 15);
  wp[e] = (_Float16)w[(co * Ci + ci) * 27 + tap];
}

__device__ __forceinline__ void linpack_one(int e, const float* __restrict__ w,
                                            _Float16* __restrict__ wl, int kb) {
  int j = e & 7; int l = (e >> 3) & 63; int r = e >> 9;
  int nt = r % 6; int kt = r / 6;
  int Ci = kb * 32;
  int ci = kt * 32 + (l >> 4) * 8 + j;
  int co = nt * 16 + (l & 15);
  wl[e] = (_Float16)w[co * Ci + ci];
}

#define WP3 (27*3*6*512)
#define WP6 (27*6*6*512)
#define WL3 (3*6*512)
#define WL6 (6*6*512)
#define WV2 (27*512)    // v-conv B-fragments: [chunk3][col9][lane64][j8]
#define PACK_TOTAL (2*WP3 + 2*WP6 + 2*WL3 + 2*WL6 + WV2)

__global__ void k_packall(
    const float* __restrict__ wq, const float* __restrict__ wh,
    const float* __restrict__ wa, const float* __restrict__ wu,
    const float* __restrict__ lq, const float* __restrict__ lh,
    const float* __restrict__ la, const float* __restrict__ lu,
    const float* __restrict__ wvc,
    _Float16* __restrict__ wpq, _Float16* __restrict__ wph,
    _Float16* __restrict__ wpa, _Float16* __restrict__ wpu,
    _Float16* __restrict__ wlq, _Float16* __restrict__ wlh,
    _Float16* __restrict__ wla, _Float16* __restrict__ wlu,
    _Float16* __restrict__ wt2) {
  int e = blockIdx.x * 256 + threadIdx.x;
  if (e < WP3) { wpack_one(e, wq, wpq, 3); return; } e -= WP3;
  if (e < WP3) { wpack_one(e, wh, wph, 3); return; } e -= WP3;
  if (e < WP6) { wpack_one(e, wa, wpa, 6); return; } e -= WP6;
  if (e < WP6) { wpack_one(e, wu, wpu, 6); return; } e -= WP6;
  if (e < WL3) { linpack_one(e, lq, wlq, 3); return; } e -= WL3;
  if (e < WL3) { linpack_one(e, lh, wlh, 3); return; } e -= WL3;
  if (e < WL6) { linpack_one(e, la, wla, 6); return; } e -= WL6;
  if (e < WL6) { linpack_one(e, lu, wlu, 6); return; } e -= WL6;
  if (e < WV2) {
    // B[k=(l>>4)*8+j][n=l&15] = (n<3) ? wvc[ci*27 + col9*3 + n] : 0
    int j = e & 7; int l = (e >> 3) & 63; int r = e >> 9;   // r in 0..26
    int col9 = r % 9, chunk = r / 9;
    int n = l & 15, kq = l >> 4;
    int ci = chunk * 32 + kq * 8 + j;
    wt2[e] = (n < 3) ? (_Float16)wvc[ci * 27 + col9 * 3 + n] : (_Float16)0.f;
  }
}

// ---------------- MFMA 3x3x3 conv ----------------
// R8: 384 threads, 6 waves = (column msel) x (cout-pair npair).
// Each wave: M=32 (column msel, both z-halves) x N=32 (couts npair*32..+32).
// Per tap: 2 A ds_reads + 2 B loads -> 4 MFMAs (2x B-reuse, 2x A-reuse).
// Block = 2 z-columns (x, y0), (x, y0+1). LDS halo 12 cols x 34 z x 32 ci f16
// (rows padded to 40) = 32640 B. Output grid f16.
// PAIR: blocks [512, 1024) run the second (gA2, wp2, out2) problem.
template<int NCH, int PAIR>   // NCH: 3 (Cin=96) or 6 (Cin=192, 2nd 96 from gB)
__global__ __launch_bounds__(384, 4) void k_conv_mfma(
    const _Float16* __restrict__ gA, const _Float16* __restrict__ gB,
    const half8* __restrict__ wp, _Float16* __restrict__ out,
    const _Float16* __restrict__ gA2, const half8* __restrict__ wp2,
    _Float16* __restrict__ out2) {
  __shared__ unsigned short ls[12 * 34 * 40];
  int bid = blockIdx.x;
  const _Float16* ga = gA; const _Float16* gb = gB;
  const half8* w = wp; _Float16* o = out;
  if (PAIR && bid >= 512) { bid -= 512; ga = gA2; gb = gA2; w = wp2; o = out2; }
  int bx = bid >> 4, y0 = (bid & 15) * 2;
  int tid = threadIdx.x;
  int lane = tid & 63, wv = tid >> 6;    // 6 waves
  int msel = wv & 1, npair = wv >> 1;    // column sel (M=32), cout pair (N=32)
  int lrow = lane & 15, quad = lane >> 4;

  f32x4 acc[2][2];   // [mt][nb]
#pragma unroll
  for (int i = 0; i < 2; ++i)
#pragma unroll
    for (int j = 0; j < 2; ++j) acc[i][j] = (f32x4){0.f, 0.f, 0.f, 0.f};

  for (int chunk = 0; chunk < NCH; ++chunk) {
    const _Float16* g = (NCH == 6 && chunk >= 3) ? gb : ga;
    int cbase = ((NCH == 6 && chunk >= 3) ? chunk - 3 : chunk) * 32;
    __syncthreads();
    for (int e = tid; e < 12 * 34 * 4; e += 384) {
      int ciu = e & 3; int zc = e >> 2;
      int zz = zc % 34; int sc = zc / 34;
      int dx = sc >> 2, dyy = sc & 3;
      int x = bx + dx - 1, y = y0 + dyy - 1, zv = zz - 1;
      uint4 val = {0u, 0u, 0u, 0u};
      if ((unsigned)x < 32u && (unsigned)y < 32u && (unsigned)zv < 32u)
        val = *reinterpret_cast<const uint4*>(
            g + (size_t)((x << 10) + (y << 5) + zv) * CH + cbase + ciu * 8);
      *reinterpret_cast<uint4*>(&ls[(sc * 34 + zz) * 40 + ciu * 8]) = val;
    }
    __syncthreads();
#pragma unroll
    for (int dx9 = 0; dx9 < 3; ++dx9)
#pragma unroll
      for (int dy9 = 0; dy9 < 3; ++dy9) {
        int sc = dx9 * 4 + msel + dy9;
        const unsigned short* lbase = &ls[(sc * 34) * 40 + quad * 8];
        int tap0 = (dx9 * 3 + dy9) * 3;
#pragma unroll
        for (int dz = 0; dz < 3; ++dz) {
          half8 a0 = *reinterpret_cast<const half8*>(&lbase[(lrow + dz) * 40]);
          half8 a1 = *reinterpret_cast<const half8*>(&lbase[(16 + lrow + dz) * 40]);
          const half8* wb = w + ((size_t)((tap0 + dz) * NCH + chunk) * 6 + npair * 2) * 64 + lane;
          half8 b0 = wb[0];
          half8 b1 = wb[64];
          acc[0][0] = __builtin_amdgcn_mfma_f32_16x16x32_f16(a0, b0, acc[0][0], 0, 0, 0);
          acc[1][0] = __builtin_amdgcn_mfma_f32_16x16x32_f16(a1, b0, acc[1][0], 0, 0, 0);
          acc[0][1] = __builtin_amdgcn_mfma_f32_16x16x32_f16(a0, b1, acc[0][1], 0, 0, 0);
          acc[1][1] = __builtin_amdgcn_mfma_f32_16x16x32_f16(a1, b1, acc[1][1], 0, 0, 0);
        }
      }
  }
  int y = y0 + msel;
  int vb = (bx << 10) + (y << 5);
#pragma unroll
  for (int mt = 0; mt < 2; ++mt)
#pragma unroll
    for (int nb = 0; nb < 2; ++nb)
#pragma unroll
      for (int r = 0; r < 4; ++r) {
        int z = mt * 16 + quad * 4 + r;
        o[(size_t)(vb + z) * CH + (npair * 2 + nb) * 16 + lrow] = (_Float16)acc[mt][nb][r];
      }
}

// Cout=1 conv (the 'v' attention head) via MFMA taps-in-N (R9).
__global__ __launch_bounds__(128) void k_conv3d_v2(
    const _Float16* __restrict__ g, const _Float16* __restrict__ wt2,
    float* __restrict__ out) {
  __shared__ unsigned short ls[12 * 48 * 32];
  __shared__ float dl[2][48][4];
  int bid = blockIdx.x;            // 512 blocks: bx = bid>>4, y0 = (bid&15)*2
  int bx = bid >> 4, y0 = (bid & 15) * 2;
  int tid = threadIdx.x;
  int lane = tid & 63, wv = tid >> 6;
  int lrow = lane & 15, quad = lane >> 4;

  f32x4 acc[3];
#pragma unroll
  for (int i = 0; i < 3; ++i) acc[i] = (f32x4){0.f, 0.f, 0.f, 0.f};

  for (int chunk = 0; chunk < 3; ++chunk) {
    __syncthreads();
#pragma unroll 3
    for (int it = 0; it < 18; ++it) {
      int e = it * 128 + tid;
      int c8 = e & 3;
      int t = e >> 2;              // col*48 + zz
      int col = t / 48;
      int zz = t - col * 48;
      int dx = col >> 2, dyy = col & 3;
      int x = bx + dx - 1, y = y0 + dyy - 1, zv = zz - 1;
      uint4 val = {0u, 0u, 0u, 0u};
      if ((unsigned)x < 32u && (unsigned)y < 32u && (unsigned)zv < 32u)
        val = *reinterpret_cast<const uint4*>(
            g + (size_t)((x << 10) + (y << 5) + zv) * CH + chunk * 32 + c8 * 8);
      *reinterpret_cast<uint4*>(&ls[(t << 5) + ((c8 ^ (zz & 3)) << 3)]) = val;
    }
    __syncthreads();
#pragma unroll
    for (int dx9 = 0; dx9 < 3; ++dx9)
#pragma unroll
      for (int dy9 = 0; dy9 < 3; ++dy9) {
        int col9 = dx9 * 3 + dy9;
        int sc = dx9 * 4 + wv + dy9;
        half8 b = *reinterpret_cast<const half8*>(
            wt2 + (size_t)((chunk * 9 + col9) << 9) + (lane << 3));
#pragma unroll
        for (int mt = 0; mt < 3; ++mt) {
          int zz = mt * 16 + lrow;
          half8 a = *reinterpret_cast<const half8*>(
              &ls[((sc * 48 + zz) << 5) + ((quad ^ (zz & 3)) << 3)]);
          acc[mt] = __builtin_amdgcn_mfma_f32_16x16x32_f16(a, b, acc[mt], 0, 0, 0);
        }
      }
  }
  if (lrow < 3) {
#pragma unroll
    for (int mt = 0; mt < 3; ++mt)
#pragma unroll
      for (int r = 0; r < 4; ++r)
        dl[wv][mt * 16 + quad * 4 + r][lrow] = acc[mt][r];
  }
  __syncthreads();
  if (tid < 64) {
    int z = tid & 31, yb = tid >> 5;
    float v = dl[yb][z][0] + dl[yb][z + 1][1] + dl[yb][z + 2][2];
    out[(bx << 10) + ((y0 + yb) << 5) + z] = v;
  }
}

// ---------------- fused point kernel: MFMA linear + trilinear devox ----------------

__device__ __forceinline__ void corner_one(
    const float* __restrict__ coords, const unsigned* __restrict__ cnt,
    int p, int k, int& flc, float& w) {
  float cx = coords[3*p], cy = coords[3*p+1], cz = coords[3*p+2];
  float bx = floorf(cx), by = floorf(cy), bz = floorf(cz);
  float fx = cx - bx, fy = cy - by, fz = cz - bz;
  int dx = (k >> 2) & 1, dy = (k >> 1) & 1, dzz = k & 1;
  int ix = (int)bx + dx, iy = (int)by + dy, iz = (int)bz + dzz;
  bool valid = ((unsigned)ix < 32u) && ((unsigned)iy < 32u) && ((unsigned)iz < 32u);
  int xc = min(max(ix, 0), 31), yc = min(max(iy, 0), 31), zc = min(max(iz, 0), 31);
  flc = (xc << 10) + (yc << 5) + zc;
  float wx = dx ? fx : 1.f - fx;
  float wy = dy ? fy : 1.f - fy;
  float wz = dzz ? fz : 1.f - fz;
  w = (valid && cnt[flc] > 0u) ? wx * wy * wz : 0.f;
}

// R10: block handles sorted slots [p0, p0+64); physical point p = order[idx].
// KB: 3 (K=96, X fp32 ORIGINAL-order inputs query/hidden, gathered via lord)
//     or 6 (K=192, X = [X1, X2] f16 SORTED streams, read sequentially).
// MODE: 0 = plain (dst = devox+lin+b, f16 SORTED out), 1 = energy (tanh, f16
//       SORTED out + attn partial -> attn_out[idx] SORTED), 2 = final (tanh;
//       X2 scaled by SORTED scale; fp32 out scattered to out[p]).
// PAIR (MODE 0 only): blocks [npt, 2npt) run (outv2, X1b, wl2, lb2 -> dst2).
template<int KB, int MODE, int PAIR>
__global__ __launch_bounds__(256) void k_point(
    const _Float16* __restrict__ outv, const void* __restrict__ X1, const void* __restrict__ X2,
    const float* __restrict__ scale, const half8* __restrict__ wl,
    const float* __restrict__ lb, const float* __restrict__ vlw,
    const float* __restrict__ coords, const unsigned* __restrict__ cnt,
    const int* __restrict__ order,
    void* __restrict__ dst, float* __restrict__ attn_out, int n,
    const _Float16* __restrict__ outv2, const void* __restrict__ X1b,
    const half8* __restrict__ wl2, const float* __restrict__ lb2,
    void* __restrict__ dst2) {
  __shared__ char us[64 * 100 * 4];   // union: f16 A-stage [64][KB*32+8] / fp32 acc [64][100]
  __shared__ int lflc[512];
  __shared__ float lcw[512];
  __shared__ int lord[64];
  constexpr int APITCH = KB * 32 + 8;
  constexpr int XF16 = (KB == 6);      // sorted f16 inter-stage streams
  constexpr int OUTF16 = (MODE != 2);  // final output stays fp32
  int tid = threadIdx.x;
  int bid = blockIdx.x;
  const _Float16* ov = outv; const void* x1 = X1;
  const half8* w = wl; const float* b = lb; void* d = dst;
  if (PAIR) {
    int npt = (n + 63) >> 6;
    if (bid >= npt) { bid -= npt; ov = outv2; x1 = X1b; w = wl2; b = lb2; d = dst2; }
  }
  int p0 = bid * 64;

  if (tid < 64) lord[tid] = (p0 + tid < n) ? order[p0 + tid] : 0;
  __syncthreads();

  // corner table (physical point p -> clustered voxels, L2-local)
  for (int e = tid; e < 512; e += 256) {
    int j = e >> 3, k = e & 7;
    int f = 0; float wgt = 0.f;
    if (p0 + j < n) corner_one(coords, cnt, lord[j], k, f, wgt);
    lflc[e] = f; lcw[e] = wgt;
  }

  // stage A (f16) into LDS
  unsigned short* lsa = reinterpret_cast<unsigned short*>(us);
  if (XF16) {
    // 16B half8 loads: KB*4 chunks per point (=24 for KB=6)
    for (int e = tid; e < 64 * KB * 4; e += 256) {
      int j = e / (KB * 4);
      int q8 = e - j * (KB * 4);
      int idx = p0 + j;
      half8 hx = {(_Float16)0.f, (_Float16)0.f, (_Float16)0.f, (_Float16)0.f,
                  (_Float16)0.f, (_Float16)0.f, (_Float16)0.f, (_Float16)0.f};
      if (idx < n) {
        if (q8 < 12) {
          hx = __builtin_nontemporal_load(reinterpret_cast<const half8*>(x1) + idx * 12 + q8);
        } else {
          hx = __builtin_nontemporal_load(reinterpret_cast<const half8*>(X2) + idx * 12 + (q8 - 12));
          if (MODE == 2) {
            float sc = scale[idx];
#pragma unroll
            for (int u = 0; u < 8; ++u) hx[u] = (_Float16)((float)hx[u] * sc);
          }
        }
      }
      *reinterpret_cast<half8*>(&lsa[j * APITCH + q8 * 8]) = hx;
    }
  } else {
    for (int e = tid; e < 64 * KB * 8; e += 256) {
      int j = e / (KB * 8);
      int q4 = e - j * (KB * 8);
      int idx = p0 + j;
      // original-order fp32 inputs: 24 consecutive threads fetch one 384B row
      f32x4 v = {0.f, 0.f, 0.f, 0.f};
      if (idx < n)
        v = __builtin_nontemporal_load(
            reinterpret_cast<const f32x4*>(x1) + (size_t)lord[j] * 24 + q4);
      union { _Float16 h; unsigned short u; } h0, h1, h2, h3;
      h0.h = (_Float16)v.x; h1.h = (_Float16)v.y; h2.h = (_Float16)v.z; h3.h = (_Float16)v.w;
      ushort4 o; o.x = h0.u; o.y = h1.u; o.z = h2.u; o.w = h3.u;
      *reinterpret_cast<ushort4*>(&lsa[j * APITCH + q4 * 4]) = o;
    }
  }
  __syncthreads();

  // MFMA: wave wv handles rows [wv*16, wv*16+16), full N=96.
  int lane = tid & 63, wv = tid >> 6;
  int lrow = lane & 15, quad = lane >> 4;
  f32x4 acc[6];
#pragma unroll
  for (int i = 0; i < 6; ++i) acc[i] = (f32x4){0.f, 0.f, 0.f, 0.f};
#pragma unroll
  for (int kt = 0; kt < KB; ++kt) {
    half8 a = *reinterpret_cast<const half8*>(&lsa[(wv * 16 + lrow) * APITCH + kt * 32 + quad * 8]);
    const half8* wb = w + (size_t)(kt * 6) * 64 + lane;
#pragma unroll
    for (int nt = 0; nt < 6; ++nt)
      acc[nt] = __builtin_amdgcn_mfma_f32_16x16x32_f16(a, wb[(size_t)nt * 64], acc[nt], 0, 0, 0);
  }
  __syncthreads();   // done reading lsa; reuse as fp32 acc
  float* lacc = reinterpret_cast<float*>(us);
#pragma unroll
  for (int nt = 0; nt < 6; ++nt)
#pragma unroll
    for (int r = 0; r < 4; ++r)
      lacc[(wv * 16 + quad * 4 + r) * 100 + nt * 16 + lrow] = acc[nt][r];
  __syncthreads();

  // point-major epilogue: 4 threads/point x 24 channels.
  int pt = tid >> 2, sub = tid & 3;
  int idx = p0 + pt;
  bool valid = idx < n;
  f32x4 a[6];
  const float* lrow_p = &lacc[pt * 100 + sub * 24];
#pragma unroll
  for (int i = 0; i < 6; ++i) a[i] = *reinterpret_cast<const f32x4*>(lrow_p + i * 4);
  const f32x4* lb4 = reinterpret_cast<const f32x4*>(b + sub * 24);
#pragma unroll
  for (int i = 0; i < 6; ++i) a[i] += lb4[i];
  // guarded 8-corner gather from the f16 grid (48B/thread/corner, L2-local).
  // Guard doubles as the VGPR throttle: without it the compiler hoists all
  // 24 half8 loads -> 92 VGPR -> occupancy collapse (R11 regression).
#pragma unroll
  for (int k = 0; k < 8; ++k) {
    float wgt = lcw[pt * 8 + k];
    if (wgt != 0.f) {
      const half8* op = reinterpret_cast<const half8*>(ov + (size_t)lflc[pt * 8 + k] * CH + sub * 24);
      half8 o0 = op[0], o1 = op[1], o2 = op[2];
      f32x4 t;
      t = (f32x4){(float)o0[0], (float)o0[1], (float)o0[2], (float)o0[3]}; a[0] += wgt * t;
      t = (f32x4){(float)o0[4], (float)o0[5], (float)o0[6], (float)o0[7]}; a[1] += wgt * t;
      t = (f32x4){(float)o1[0], (float)o1[1], (float)o1[2], (float)o1[3]}; a[2] += wgt * t;
      t = (f32x4){(float)o1[4], (float)o1[5], (float)o1[6], (float)o1[7]}; a[3] += wgt * t;
      t = (f32x4){(float)o2[0], (float)o2[1], (float)o2[2], (float)o2[3]}; a[4] += wgt * t;
      t = (f32x4){(float)o2[4], (float)o2[5], (float)o2[6], (float)o2[7]}; a[5] += wgt * t;
    }
  }
  if (MODE >= 1) {
#pragma unroll
    for (int i = 0; i < 6; ++i) {
      a[i].x = tanhf(a[i].x); a[i].y = tanhf(a[i].y);
      a[i].z = tanhf(a[i].z); a[i].w = tanhf(a[i].w);
    }
  }
  if (valid) {
    if (OUTF16) {
      // sorted f16 stream out
      _Float16* dh = reinterpret_cast<_Float16*>(d) + (size_t)idx * CH + sub * 24;
      uint4* du = reinterpret_cast<uint4*>(dh);
#pragma unroll
      for (int i = 0; i < 3; ++i) {
        union { _Float16 h[8]; uint4 q; } t;
        t.h[0] = (_Float16)a[2*i].x;   t.h[1] = (_Float16)a[2*i].y;
        t.h[2] = (_Float16)a[2*i].z;   t.h[3] = (_Float16)a[2*i].w;
        t.h[4] = (_Float16)a[2*i+1].x; t.h[5] = (_Float16)a[2*i+1].y;
        t.h[6] = (_Float16)a[2*i+1].z; t.h[7] = (_Float16)a[2*i+1].w;
        du[i] = t.q;
      }
    } else {
      // final output: scatter full 384B fp32 row to original position
      f32x4* d4 = reinterpret_cast<f32x4*>(d) + (size_t)lord[pt] * 24 + sub * 6;
#pragma unroll
      for (int i = 0; i < 6; ++i) d4[i] = a[i];
    }
  }
  if (MODE == 1) {
    const f32x4* vw4 = reinterpret_cast<const f32x4*>(vlw + sub * 24);
    float partial = 0.f;
#pragma unroll
    for (int i = 0; i < 6; ++i) {
      f32x4 vw = vw4[i];
      partial += a[i].x * vw.x + a[i].y * vw.y + a[i].z * vw.z + a[i].w * vw.w;
    }
    partial += __shfl_xor(partial, 1);
    partial += __shfl_xor(partial, 2);
    if (sub == 0 && valid) attn_out[idx] = partial;   // sorted
  }
}

// attn (sorted) += v_lb + trilinear(Ov); physical point via order[].
__global__ void k_attn_final(const float* __restrict__ outvV, const float* __restrict__ vlb,
                             const float* __restrict__ coords, const unsigned* __restrict__ cnt,
                             const int* __restrict__ order,
                             float* __restrict__ attn, int n) {
  int idx = blockIdx.x * 256 + threadIdx.x;
  if (idx >= n) return;
  int p = order[idx];
  float a = attn[idx] + vlb[0];
#pragma unroll
  for (int k = 0; k < 8; ++k) {
    int f; float w;
    corner_one(coords, cnt, p, k, f, w);
    a += w * outvV[f];
  }
  attn[idx] = a;
}

// ---------------- launch ----------------

extern "C" void kernel_launch(void* const* d_in, const int* in_sizes, int n_in,
                              void* d_out, int out_size, void* d_ws, size_t ws_size,
                              hipStream_t stream) {
  const float* hidden   = (const float*)d_in[0];
  const float* query    = (const float*)d_in[1];
  const float* coords   = (const float*)d_in[2];
  const float* wq_conv  = (const float*)d_in[3];
  const float* wq_lw    = (const float*)d_in[4];
  const float* wq_lb    = (const float*)d_in[5];
  const float* wh_conv  = (const float*)d_in[6];
  const float* wh_lw    = (const float*)d_in[7];
  const float* wh_lb    = (const float*)d_in[8];
  const float* att_conv = (const float*)d_in[9];
  const float* att_lw   = (const float*)d_in[10];
  const float* att_lb   = (const float*)d_in[11];
  const float* v_conv   = (const float*)d_in[12];
  const float* v_lw     = (const float*)d_in[13];
  const float* v_lb     = (const float*)d_in[14];
  const float* upd_conv = (const float*)d_in[15];
  const float* upd_lw   = (const float*)d_in[16];
  const float* upd_lb   = (const float*)d_in[17];
  float* out = (float*)d_out;
  const int n = in_sizes[0] / CH;

  char* wsp = (char*)d_ws;
  auto alloc = [&](size_t bytes) {
    char* r = wsp;
    wsp += (bytes + 255) & ~(size_t)255;
    return r;
  };
  int*      flat  = (int*)     alloc((size_t)n * 4);
  int*      order = (int*)     alloc((size_t)n * 4);
  unsigned* cnt   = (unsigned*)alloc((size_t)NV * 4);
  unsigned* base  = (unsigned*)alloc((size_t)NV * 4);
  unsigned* cur   = (unsigned*)alloc((size_t)NV * 4);
  float*    inv   = (float*)   alloc((size_t)NV * 4);
  float*    attn  = (float*)   alloc((size_t)n * 4);   // SORTED order
  _Float16* wt2   = (_Float16*)alloc((size_t)WV2 * 2);
  _Float16* wpq = (_Float16*)alloc((size_t)WP3 * 2);
  _Float16* wph = (_Float16*)alloc((size_t)WP3 * 2);
  _Float16* wpa = (_Float16*)alloc((size_t)WP6 * 2);
  _Float16* wpu = (_Float16*)alloc((size_t)WP6 * 2);
  _Float16* wlq = (_Float16*)alloc((size_t)WL3 * 2);
  _Float16* wlh = (_Float16*)alloc((size_t)WL3 * 2);
  _Float16* wla = (_Float16*)alloc((size_t)WL6 * 2);
  _Float16* wlu = (_Float16*)alloc((size_t)WL6 * 2);
  _Float16* Hq  = (_Float16*)alloc((size_t)NV * CH * 2);
  _Float16* Hh  = (_Float16*)alloc((size_t)NV * CH * 2);
  _Float16* H1  = (_Float16*)alloc((size_t)NV * CH * 2);
  _Float16* H2  = (_Float16*)alloc((size_t)NV * CH * 2);
  _Float16* O1  = (_Float16*)alloc((size_t)NV * CH * 2);
  _Float16* O2  = (_Float16*)alloc((size_t)NV * CH * 2);
  float* Ov   = (float*)alloc((size_t)NV * 4);
  _Float16* qv   = (_Float16*)alloc((size_t)n * CH * 2);   // SORTED order
  _Float16* hv   = (_Float16*)alloc((size_t)n * CH * 2);   // SORTED order
  _Float16* ebuf = (_Float16*)alloc((size_t)n * CH * 2);   // SORTED order

  const int nb  = (n + 255) / 256;
  const int npt = (n + 63) / 64;
  const int nva   = NV * 24 / 256;   // 3072 (fp32 source: 24 chunks)
  const int nva16 = NV * 12 / 256;   // 1536 (f16 source: 12 half8 chunks)

  // prep: CSR + merged weight packing
  hipMemsetAsync(cnt, 0, (size_t)NV * 4, stream);
  k_prep<<<nb, 256, 0, stream>>>(coords, flat, cnt, n);
  k_scan<<<1, 1024, 0, stream>>>(cnt, base, cur, inv);
  k_fill<<<nb, 256, 0, stream>>>(flat, cur, order, n);
  k_packall<<<(PACK_TOTAL + 255) / 256, 256, 0, stream>>>(
      wq_conv, wh_conv, att_conv, upd_conv, wq_lw, wh_lw, att_lw, upd_lw, v_conv,
      wpq, wph, wpa, wpu, wlq, wlh, wla, wlu, wt2);

  // stages 1+2 (merged): q = sconv(query), h = sconv(hidden)
  k_voxavg<0,1,0,0><<<2*nva, 256, 0, stream>>>(query, nullptr, base, cnt, inv, order,
                                               Hq, hidden, Hh);
  k_conv_mfma<3,1><<<1024, 384, 0, stream>>>(Hq, Hq, (const half8*)wpq, O1,
                                             Hh, (const half8*)wph, O2);
  k_point<3,0,1><<<2*npt, 256, 0, stream>>>(O1, query, nullptr, nullptr, (const half8*)wlq,
                                            wq_lb, nullptr, coords, cnt, order, qv, nullptr, n,
                                            O2, hidden, (const half8*)wlh, wh_lb, hv);

  // stage 3: energy = tanh(sconv([h,q])) -> ebuf (f16 sorted) + v partial (attn sorted)
  k_voxavg<0,1,1,1><<<2*nva16, 256, 0, stream>>>(hv, nullptr, base, cnt, inv, order,
                                                 H1, qv, H2);
  k_conv_mfma<6,0><<<512, 384, 0, stream>>>(H1, H2, (const half8*)wpa, O1,
                                            nullptr, nullptr, nullptr);
  k_point<6,1,0><<<npt, 256, 0, stream>>>(O1, hv, qv, nullptr, (const half8*)wla,
                                          att_lb, v_lw, coords, cnt, order, ebuf, attn, n,
                                          nullptr, nullptr, nullptr, nullptr, nullptr);

  // stage 4: attn = sconv(energy) with Cout=1 (f16 grid, MFMA taps-in-N)
  k_voxavg<0,0,1,1><<<nva16, 256, 0, stream>>>(ebuf, nullptr, base, cnt, inv, order,
                                               Hq, nullptr, nullptr);
  k_conv3d_v2<<<512, 128, 0, stream>>>(Hq, wt2, Ov);
  k_attn_final<<<nb, 256, 0, stream>>>(Ov, v_lb, coords, cnt, order, attn, n);

  // stage 5: out = tanh(sconv([q, attn*h]))
  k_voxavg<1,0,1,1><<<nva16, 256, 0, stream>>>(hv, attn, base, cnt, inv, order,
                                               H1, nullptr, nullptr);
  k_conv_mfma<6,0><<<512, 384, 0, stream>>>(H2, H1, (const half8*)wpu, O1,
                                            nullptr, nullptr, nullptr);
  k_point<6,2,0><<<npt, 256, 0, stream>>>(O1, qv, hv, attn, (const half8*)wlu,
                                          upd_lb, nullptr, coords, cnt, order, out, nullptr, n,
                                          nullptr, nullptr, nullptr, nullptr, nullptr);
}